// Round 6
// baseline (726.954 us; speedup 1.0000x reference)
//
#include <hip/hip_runtime.h>
#include <math.h>

// Problem constants
#define B_   16
#define C_   64
#define OC_  64
#define H_   128
#define W_   128
#define E_   4
#define HID_ 16
#define HW_  (H_ * W_)          // 16384
#define TEMP_ 30.0f

// Activation plane: [kind(h=0,l=1)][chunk(0,1)][b][hw][32ch], bf16.
#define PSTR ((size_t)B_ * HW_ * 32)

typedef float f32x4 __attribute__((ext_vector_type(4)));
typedef short s16x8 __attribute__((ext_vector_type(8)));
typedef short s16x4 __attribute__((ext_vector_type(4)));

__device__ __forceinline__ unsigned short f2bf(float f) {
    unsigned u = __float_as_uint(f);
    u = u + 0x7FFFu + ((u >> 16) & 1u);          // round-to-nearest-even
    return (unsigned short)(u >> 16);
}
__device__ __forceinline__ float bf2f(unsigned short h) {
    return __uint_as_float(((unsigned)h) << 16);
}

// ---------------------------------------------------------------------------
// K1: global average pool. One block per (b,c).
// ---------------------------------------------------------------------------
__global__ void pool_kernel(const float* __restrict__ x, float* __restrict__ pooled) {
    int bc = blockIdx.x;
    const float4* xp = (const float4*)(x + (size_t)bc * HW_);
    float s = 0.f;
    for (int i = threadIdx.x; i < HW_ / 4; i += 256) {
        float4 v = xp[i];
        s += v.x + v.y + v.z + v.w;
    }
    for (int off = 32; off; off >>= 1) s += __shfl_down(s, off, 64);
    __shared__ float red[4];
    int lane = threadIdx.x & 63, wv = threadIdx.x >> 6;
    if (lane == 0) red[wv] = s;
    __syncthreads();
    if (threadIdx.x == 0)
        pooled[bc] = (red[0] + red[1] + red[2] + red[3]) * (1.0f / (float)HW_);
}

// ---------------------------------------------------------------------------
// K2: control MLP + softmax + mixed biases (3 layers). grid=B_, block=64.
// ---------------------------------------------------------------------------
__global__ void control_kernel(const float* __restrict__ pooled,
                               const float* __restrict__ cw1,
                               const float* __restrict__ cw2,
                               const float* __restrict__ b1,
                               const float* __restrict__ b2,
                               const float* __restrict__ b3,
                               float* __restrict__ coeff,
                               float* __restrict__ ab_all) {
    int b = blockIdx.x;
    int t = threadIdx.x;                // oc
    __shared__ float pl[C_];
    __shared__ float hid[HID_];
    pl[t] = pooled[b * C_ + t];
    __syncthreads();
    if (t < HID_) {
        float a = 0.f;
        for (int c = 0; c < C_; ++c) a = fmaf(pl[c], cw1[t * C_ + c], a);
        hid[t] = fmaxf(a, 0.f);
    }
    __syncthreads();
    float l[E_];
#pragma unroll
    for (int e = 0; e < E_; ++e) {
        float a = 0.f;
#pragma unroll
        for (int h = 0; h < HID_; ++h) a = fmaf(hid[h], cw2[(t * E_ + e) * HID_ + h], a);
        l[e] = a * (1.0f / TEMP_);
    }
    float m = fmaxf(fmaxf(l[0], l[1]), fmaxf(l[2], l[3]));
    float p[E_], s = 0.f;
#pragma unroll
    for (int e = 0; e < E_; ++e) { p[e] = expf(l[e] - m); s += p[e]; }
    float inv = 1.0f / s;
#pragma unroll
    for (int e = 0; e < E_; ++e) { p[e] *= inv; coeff[(b * OC_ + t) * E_ + e] = p[e]; }
    float a1 = 0.f, a2 = 0.f, a3 = 0.f;
#pragma unroll
    for (int e = 0; e < E_; ++e) {
        a1 = fmaf(p[e], b1[e * OC_ + t], a1);
        a2 = fmaf(p[e], b2[e * OC_ + t], a2);
        a3 = fmaf(p[e], b3[e * OC_ + t], a3);
    }
    ab_all[0 * B_ * OC_ + b * OC_ + t] = a1;
    ab_all[1 * B_ * OC_ + b * OC_ + t] = a2;
    ab_all[2 * B_ * OC_ + b * OC_ + t] = a3;
}

// ---------------------------------------------------------------------------
// K3: mix expert weights, split to bf16 hi/lo, reorder to [b][oc][tap][64c].
// ---------------------------------------------------------------------------
__global__ void aggw_split(const float* __restrict__ coeff,
                           const float* __restrict__ w1,
                           const float* __restrict__ w2,
                           const float* __restrict__ w3,
                           unsigned short* __restrict__ Wh1, unsigned short* __restrict__ Wl1,
                           unsigned short* __restrict__ Wh2, unsigned short* __restrict__ Wl2,
                           unsigned short* __restrict__ Wh3, unsigned short* __restrict__ Wl3) {
    int layer = blockIdx.y;
    const float* w = (layer == 0) ? w1 : (layer == 1) ? w2 : w3;
    unsigned short* Wh = (layer == 0) ? Wh1 : (layer == 1) ? Wh2 : Wh3;
    unsigned short* Wl = (layer == 0) ? Wl1 : (layer == 1) ? Wl2 : Wl3;

    int idx = blockIdx.x * 256 + threadIdx.x;     // < 589824
    int c   = idx & 63;
    int r   = idx >> 6;
    int tap = r % 9;
    int r2  = r / 9;
    int oc  = r2 & 63;
    int b   = r2 >> 6;

    float s = 0.f;
#pragma unroll
    for (int e = 0; e < E_; ++e)
        s = fmaf(coeff[(b * OC_ + oc) * E_ + e],
                 w[(((size_t)e * OC_ + oc) * C_ + c) * 9 + tap], s);
    unsigned short h = f2bf(s);
    Wh[idx] = h;
    Wl[idx] = f2bf(s - bf2f(h));
}

// ---------------------------------------------------------------------------
// K4: convert+transpose x: fp32 [b][c][hw] -> 4 bf16 planes [k][chunk][b][hw][32].
// ---------------------------------------------------------------------------
__global__ void xcvt_kernel(const float* __restrict__ x,
                            unsigned short* __restrict__ Xs) {
    __shared__ float tr[64][65];
    const int b   = blockIdx.y;
    const int hw0 = blockIdx.x * 64;
    const int t   = threadIdx.x;
    const int l   = t & 63;
    const int wv  = t >> 6;
    const float* src = x + (size_t)b * C_ * HW_;
#pragma unroll
    for (int i = 0; i < 16; ++i) {
        int c = wv * 16 + i;
        tr[l][c] = src[(size_t)c * HW_ + hw0 + l];
    }
    __syncthreads();
#pragma unroll
    for (int i = 0; i < 2; ++i) {
        int g  = t + i * 256;                 // < 512
        int px = g >> 3;
        int cg = (g & 7) << 3;
        s16x8 hv, lv;
#pragma unroll
        for (int j = 0; j < 8; ++j) {
            float v = tr[px][cg + j];
            unsigned short h = f2bf(v);
            hv[j] = (short)h;
            lv[j] = (short)f2bf(v - bf2f(h));
        }
        int chunk = cg >> 5;
        int off   = cg & 31;
        size_t base = ((size_t)b * HW_ + hw0 + px) * 32 + off;
        *(s16x8*)(Xs + (size_t)(0 + chunk) * PSTR + base) = hv;
        *(s16x8*)(Xs + (size_t)(2 + chunk) * PSTR + base) = lv;
    }
}

// ---------------------------------------------------------------------------
// K5 v3: split-bf16 MFMA conv, latency-pipelined.
// Grid 1024 (XCD-swizzled), 512 thr (8 waves).
// Block: sample b, 2 output rows x 128 px, 64 oc.
// Wave wv: rw=wv&1 (row), hx=(wv>>1)&1 (px half, 4 nt of 16), oh=wv>>2 (oc half,
// 2 oct of 16). acc[2][4].
// LDS: DOUBLE-buffered X tile [4 rows][65 pairs][8 slots][8ch] = 2 x 33,280 B.
// Phase p = plane p (h-c0, h-c1, l-c0, l-c1). Schedule per phase:
//   barrier -> ds_write(phase p+1, loads long arrived) -> issue loads(p+2)
//   -> tap loop (reads buf[p&1], weight ping-pong from L2).
// Staging latency hides under the previous phase's tap loop (T14).
// ---------------------------------------------------------------------------
#define NGRAN 2080                 // 4*65*8 16B-granules per phase
__launch_bounds__(512, 4)
__global__ void conv_mfma(const unsigned short* __restrict__ Xs,
                          const unsigned short* __restrict__ Wh,
                          const unsigned short* __restrict__ Wl,
                          const float* __restrict__ bias,
                          unsigned short* __restrict__ Ys,
                          float* __restrict__ Yf,
                          int final_layer) {
    const int bid  = blockIdx.x;
    const int wg   = (bid & 7) * 128 + (bid >> 3);   // XCD-bijective swizzle
    const int b    = wg >> 6;
    const int py0  = (wg & 63) * 2;

    const int t  = threadIdx.x;
    const int l  = t & 63;
    const int wv = t >> 6;
    const int lq = l >> 4;
    const int ln = l & 15;
    const int rw = wv & 1;
    const int hx = (wv >> 1) & 1;
    const int oh = wv >> 2;

    __shared__ __align__(16) unsigned short lds_x[2][NGRAN * 8];   // 2 x 33,280 B

    f32x4 acc[2][4];
#pragma unroll
    for (int o = 0; o < 2; ++o)
#pragma unroll
        for (int n = 0; n < 4; ++n)
#pragma unroll
            for (int r = 0; r < 4; ++r) acc[o][n][r] = 0.f;

    const size_t pbase = (size_t)b * HW_ * 32;
    const size_t wbase = (size_t)b * OC_ * 9 * 64;

    s16x8 stg[5];

    // issue global loads for plane ph into stg regs
#define ISSUE(ph)                                                              \
    {                                                                          \
        const unsigned short* pl_ = Xs + (size_t)(ph) * PSTR + pbase;          \
        _Pragma("unroll")                                                      \
        for (int i = 0; i < 5; ++i) {                                          \
            if (i < 4 || t < (NGRAN - 2048)) {                                 \
                int g = t + i * 512;                                           \
                int s_lin = g & 7;                                             \
                int pr    = (g >> 3) % 65;                                     \
                int row   = (g >> 3) / 65;                                     \
                int u = s_lin >> 2, q = s_lin & 3;                             \
                int ic = 2 * pr + u - 1;                                       \
                int ir = py0 + row - 1;                                        \
                s16x8 v;                                                       \
                _Pragma("unroll")                                              \
                for (int j = 0; j < 8; ++j) v[j] = 0;                          \
                if ((unsigned)ir < (unsigned)H_ && (unsigned)ic < (unsigned)W_)\
                    v = *(const s16x8*)(pl_ + ((size_t)(ir * W_ + ic)) * 32 + q * 8); \
                stg[i] = v;                                                    \
            }                                                                  \
        }                                                                      \
    }

    // write stg regs into LDS buffer bf (offset recomputed, no extra regs)
#define WRITE_STG(bf)                                                          \
    {                                                                          \
        _Pragma("unroll")                                                      \
        for (int i = 0; i < 5; ++i) {                                          \
            if (i < 4 || t < (NGRAN - 2048)) {                                 \
                int g = t + i * 512;                                           \
                int s_lin = g & 7;                                             \
                int pr    = (g >> 3) % 65;                                     \
                int row   = (g >> 3) / 65;                                     \
                int off   = (((row * 65 + pr) << 3) + (s_lin ^ (pr & 7))) << 3;\
                *(s16x8*)&lds_x[bf][off] = stg[i];                             \
            }                                                                  \
        }                                                                      \
    }

    // prologue
    ISSUE(0);
    WRITE_STG(0);          // waits vmcnt once (~L3 latency, once per block)
    ISSUE(1);

#pragma unroll
    for (int p = 0; p < 4; ++p) {
        const int hi    = (p < 2);
        const int cbase = (p & 1) * 32;

        __syncthreads();                 // buf[p&1] ready; buf[(p+1)&1] free
        if (p < 3) WRITE_STG((p + 1) & 1);   // stg(p+1) arrived during prev taps
        if (p < 2) ISSUE(p + 2);             // in flight during this tap loop

        // ---- tap loop: weights ping-pong from global (L2-resident) ----
        s16x8 Ah[2][2], Al[2][2];
#define LOADA(tp, pp)                                                          \
        {                                                                      \
            _Pragma("unroll")                                                  \
            for (int o = 0; o < 2; ++o) {                                      \
                size_t off = wbase + ((size_t)(((oh * 2 + o) * 16 + ln) * 9 + (tp))) * 64 \
                             + cbase + lq * 8;                                 \
                Ah[pp][o] = *(const s16x8*)(Wh + off);                         \
                if (hi) Al[pp][o] = *(const s16x8*)(Wl + off);                 \
            }                                                                  \
        }
        LOADA(0, 0);
#pragma unroll
        for (int tap = 0; tap < 9; ++tap) {
            const int pp = tap & 1;
            if (tap < 8) LOADA(tap + 1, pp ^ 1);
            const int ky  = tap / 3;
            const int kx  = tap % 3;
            const int row = rw + ky;
            s16x8 Bv[4];
#pragma unroll
            for (int nt = 0; nt < 4; ++nt) {
                int col  = hx * 64 + nt * 16 + ln + kx;      // 0..129
                int pr   = col >> 1, u = col & 1;
                int slot = (u * 4 + lq) ^ (pr & 7);
                Bv[nt] = *(const s16x8*)&lds_x[p & 1][(((row * 65 + pr) << 3) + slot) << 3];
            }
#pragma unroll
            for (int o = 0; o < 2; ++o)
#pragma unroll
                for (int nt = 0; nt < 4; ++nt)
                    acc[o][nt] = __builtin_amdgcn_mfma_f32_16x16x32_bf16(
                        Ah[pp][o], Bv[nt], acc[o][nt], 0, 0, 0);
            if (hi) {
#pragma unroll
                for (int o = 0; o < 2; ++o)
#pragma unroll
                    for (int nt = 0; nt < 4; ++nt)
                        acc[o][nt] = __builtin_amdgcn_mfma_f32_16x16x32_bf16(
                            Al[pp][o], Bv[nt], acc[o][nt], 0, 0, 0);
            }
        }
#undef LOADA
    }

    // ---- epilogue: bias + store ----
    float bia[2][4];
#pragma unroll
    for (int o = 0; o < 2; ++o)
#pragma unroll
        for (int r = 0; r < 4; ++r)
            bia[o][r] = bias[b * OC_ + (oh * 2 + o) * 16 + lq * 4 + r];

    const int orow = py0 + rw;
    if (!final_layer) {
#pragma unroll
        for (int o = 0; o < 2; ++o)
#pragma unroll
            for (int nt = 0; nt < 4; ++nt) {
                int px = hx * 64 + nt * 16 + ln;
                size_t pxl = (size_t)b * HW_ + orow * W_ + px;
                int oc0   = (oh * 2 + o) * 16 + lq * 4;
                int chunk = oc0 >> 5;
                int off   = oc0 & 31;
                s16x4 hv, lv;
#pragma unroll
                for (int r = 0; r < 4; ++r) {
                    float v = acc[o][nt][r] + bia[o][r];
                    unsigned short h = f2bf(v);
                    hv[r] = (short)h;
                    lv[r] = (short)f2bf(v - bf2f(h));
                }
                *(s16x4*)(Ys + (size_t)(0 + chunk) * PSTR + pxl * 32 + off) = hv;
                *(s16x4*)(Ys + (size_t)(2 + chunk) * PSTR + pxl * 32 + off) = lv;
            }
    } else {
#pragma unroll
        for (int o = 0; o < 2; ++o)
#pragma unroll
            for (int nt = 0; nt < 4; ++nt) {
                int px = hx * 64 + nt * 16 + ln;
#pragma unroll
                for (int r = 0; r < 4; ++r) {
                    int oc = (oh * 2 + o) * 16 + lq * 4 + r;
                    Yf[((size_t)(b * OC_ + oc)) * HW_ + orow * W_ + px] =
                        acc[o][nt][r] + bia[o][r];
                }
            }
    }
#undef ISSUE
#undef WRITE_STG
}

// ---------------------------------------------------------------------------
// Launch
// ---------------------------------------------------------------------------
extern "C" void kernel_launch(void* const* d_in, const int* in_sizes, int n_in,
                              void* d_out, int out_size, void* d_ws, size_t ws_size,
                              hipStream_t stream) {
    const float* x   = (const float*)d_in[0];
    const float* cw1 = (const float*)d_in[1];
    const float* cw2 = (const float*)d_in[2];
    const float* w1  = (const float*)d_in[3];
    const float* w2  = (const float*)d_in[4];
    const float* w3  = (const float*)d_in[5];
    const float* b1  = (const float*)d_in[6];
    const float* b2  = (const float*)d_in[7];
    const float* b3  = (const float*)d_in[8];

    char* ws = (char*)d_ws;
    float* pooled = (float*)(ws + 0);            //  4 KB
    float* coeff  = (float*)(ws + 4096);         // 16 KB
    float* ab_all = (float*)(ws + 20480);        // 12 KB
    const size_t WSZ = (size_t)B_ * OC_ * 9 * 64 * 2;   // 1,179,648 B per W array
    unsigned short* Wh1 = (unsigned short*)(ws + 32768);
    unsigned short* Wl1 = (unsigned short*)(ws + 32768 + 1 * WSZ);
    unsigned short* Wh2 = (unsigned short*)(ws + 32768 + 2 * WSZ);
    unsigned short* Wl2 = (unsigned short*)(ws + 32768 + 3 * WSZ);
    unsigned short* Wh3 = (unsigned short*)(ws + 32768 + 4 * WSZ);
    unsigned short* Wl3 = (unsigned short*)(ws + 32768 + 5 * WSZ);
    const size_t SOFF = 32768 + 6 * WSZ;                 // 7,110,656
    const size_t SSZ  = 4 * PSTR * 2;                    // 67,108,864 B per stage
    unsigned short* S0 = (unsigned short*)(ws + SOFF);
    unsigned short* S1 = (unsigned short*)(ws + SOFF + SSZ);
    // total = 141,328,384 B (unchanged)

    float* ab1 = ab_all;
    float* ab2 = ab_all + B_ * OC_;
    float* ab3 = ab_all + 2 * B_ * OC_;

    pool_kernel<<<B_ * C_, 256, 0, stream>>>(x, pooled);
    control_kernel<<<B_, 64, 0, stream>>>(pooled, cw1, cw2, b1, b2, b3, coeff, ab_all);
    {
        dim3 g(2304, 3);
        aggw_split<<<g, 256, 0, stream>>>(coeff, w1, w2, w3,
                                          Wh1, Wl1, Wh2, Wl2, Wh3, Wl3);
    }
    {
        dim3 g(HW_ / 64, B_);
        xcvt_kernel<<<g, 256, 0, stream>>>(x, S0);
    }
    conv_mfma<<<1024, 512, 0, stream>>>(S0, Wh1, Wl1, ab1, S1, nullptr, 0);
    conv_mfma<<<1024, 512, 0, stream>>>(S1, Wh2, Wl2, ab2, S0, nullptr, 0);
    conv_mfma<<<1024, 512, 0, stream>>>(S0, Wh3, Wl3, ab3, nullptr, (float*)d_out, 1);
}

// Round 7
// 618.753 us; speedup vs baseline: 1.1749x; 1.1749x over previous
//
#include <hip/hip_runtime.h>
#include <math.h>

// Problem constants
#define B_   16
#define C_   64
#define OC_  64
#define H_   128
#define W_   128
#define E_   4
#define HID_ 16
#define HW_  (H_ * W_)          // 16384
#define TEMP_ 30.0f

// Activation plane: [kind(h=0,l=1)][chunk(0,1)][b][hw][32ch], bf16.
#define PSTR ((size_t)B_ * HW_ * 32)

typedef float f32x4 __attribute__((ext_vector_type(4)));
typedef short s16x8 __attribute__((ext_vector_type(8)));
typedef short s16x4 __attribute__((ext_vector_type(4)));

__device__ __forceinline__ unsigned short f2bf(float f) {
    unsigned u = __float_as_uint(f);
    u = u + 0x7FFFu + ((u >> 16) & 1u);          // round-to-nearest-even
    return (unsigned short)(u >> 16);
}
__device__ __forceinline__ float bf2f(unsigned short h) {
    return __uint_as_float(((unsigned)h) << 16);
}

// ---------------------------------------------------------------------------
// K1: global average pool. One block per (b,c).
// ---------------------------------------------------------------------------
__global__ void pool_kernel(const float* __restrict__ x, float* __restrict__ pooled) {
    int bc = blockIdx.x;
    const float4* xp = (const float4*)(x + (size_t)bc * HW_);
    float s = 0.f;
    for (int i = threadIdx.x; i < HW_ / 4; i += 256) {
        float4 v = xp[i];
        s += v.x + v.y + v.z + v.w;
    }
    for (int off = 32; off; off >>= 1) s += __shfl_down(s, off, 64);
    __shared__ float red[4];
    int lane = threadIdx.x & 63, wv = threadIdx.x >> 6;
    if (lane == 0) red[wv] = s;
    __syncthreads();
    if (threadIdx.x == 0)
        pooled[bc] = (red[0] + red[1] + red[2] + red[3]) * (1.0f / (float)HW_);
}

// ---------------------------------------------------------------------------
// K2: control MLP + softmax + mixed biases (3 layers). grid=B_, block=64.
// ---------------------------------------------------------------------------
__global__ void control_kernel(const float* __restrict__ pooled,
                               const float* __restrict__ cw1,
                               const float* __restrict__ cw2,
                               const float* __restrict__ b1,
                               const float* __restrict__ b2,
                               const float* __restrict__ b3,
                               float* __restrict__ coeff,
                               float* __restrict__ ab_all) {
    int b = blockIdx.x;
    int t = threadIdx.x;                // oc
    __shared__ float pl[C_];
    __shared__ float hid[HID_];
    pl[t] = pooled[b * C_ + t];
    __syncthreads();
    if (t < HID_) {
        float a = 0.f;
        for (int c = 0; c < C_; ++c) a = fmaf(pl[c], cw1[t * C_ + c], a);
        hid[t] = fmaxf(a, 0.f);
    }
    __syncthreads();
    float l[E_];
#pragma unroll
    for (int e = 0; e < E_; ++e) {
        float a = 0.f;
#pragma unroll
        for (int h = 0; h < HID_; ++h) a = fmaf(hid[h], cw2[(t * E_ + e) * HID_ + h], a);
        l[e] = a * (1.0f / TEMP_);
    }
    float m = fmaxf(fmaxf(l[0], l[1]), fmaxf(l[2], l[3]));
    float p[E_], s = 0.f;
#pragma unroll
    for (int e = 0; e < E_; ++e) { p[e] = expf(l[e] - m); s += p[e]; }
    float inv = 1.0f / s;
#pragma unroll
    for (int e = 0; e < E_; ++e) { p[e] *= inv; coeff[(b * OC_ + t) * E_ + e] = p[e]; }
    float a1 = 0.f, a2 = 0.f, a3 = 0.f;
#pragma unroll
    for (int e = 0; e < E_; ++e) {
        a1 = fmaf(p[e], b1[e * OC_ + t], a1);
        a2 = fmaf(p[e], b2[e * OC_ + t], a2);
        a3 = fmaf(p[e], b3[e * OC_ + t], a3);
    }
    ab_all[0 * B_ * OC_ + b * OC_ + t] = a1;
    ab_all[1 * B_ * OC_ + b * OC_ + t] = a2;
    ab_all[2 * B_ * OC_ + b * OC_ + t] = a3;
}

// ---------------------------------------------------------------------------
// K3: mix expert weights, split to bf16 hi/lo, reorder to [b][oc][tap][64c].
// ---------------------------------------------------------------------------
__global__ void aggw_split(const float* __restrict__ coeff,
                           const float* __restrict__ w1,
                           const float* __restrict__ w2,
                           const float* __restrict__ w3,
                           unsigned short* __restrict__ Wh1, unsigned short* __restrict__ Wl1,
                           unsigned short* __restrict__ Wh2, unsigned short* __restrict__ Wl2,
                           unsigned short* __restrict__ Wh3, unsigned short* __restrict__ Wl3) {
    int layer = blockIdx.y;
    const float* w = (layer == 0) ? w1 : (layer == 1) ? w2 : w3;
    unsigned short* Wh = (layer == 0) ? Wh1 : (layer == 1) ? Wh2 : Wh3;
    unsigned short* Wl = (layer == 0) ? Wl1 : (layer == 1) ? Wl2 : Wl3;

    int idx = blockIdx.x * 256 + threadIdx.x;     // < 589824
    int c   = idx & 63;
    int r   = idx >> 6;
    int tap = r % 9;
    int r2  = r / 9;
    int oc  = r2 & 63;
    int b   = r2 >> 6;

    float s = 0.f;
#pragma unroll
    for (int e = 0; e < E_; ++e)
        s = fmaf(coeff[(b * OC_ + oc) * E_ + e],
                 w[(((size_t)e * OC_ + oc) * C_ + c) * 9 + tap], s);
    unsigned short h = f2bf(s);
    Wh[idx] = h;
    Wl[idx] = f2bf(s - bf2f(h));
}

// ---------------------------------------------------------------------------
// K4: convert+transpose x: fp32 [b][c][hw] -> 4 bf16 planes [k][chunk][b][hw][32].
// ---------------------------------------------------------------------------
__global__ void xcvt_kernel(const float* __restrict__ x,
                            unsigned short* __restrict__ Xs) {
    __shared__ float tr[64][65];
    const int b   = blockIdx.y;
    const int hw0 = blockIdx.x * 64;
    const int t   = threadIdx.x;
    const int l   = t & 63;
    const int wv  = t >> 6;
    const float* src = x + (size_t)b * C_ * HW_;
#pragma unroll
    for (int i = 0; i < 16; ++i) {
        int c = wv * 16 + i;
        tr[l][c] = src[(size_t)c * HW_ + hw0 + l];
    }
    __syncthreads();
#pragma unroll
    for (int i = 0; i < 2; ++i) {
        int g  = t + i * 256;                 // < 512
        int px = g >> 3;
        int cg = (g & 7) << 3;
        s16x8 hv, lv;
#pragma unroll
        for (int j = 0; j < 8; ++j) {
            float v = tr[px][cg + j];
            unsigned short h = f2bf(v);
            hv[j] = (short)h;
            lv[j] = (short)f2bf(v - bf2f(h));
        }
        int chunk = cg >> 5;
        int off   = cg & 31;
        size_t base = ((size_t)b * HW_ + hw0 + px) * 32 + off;
        *(s16x8*)(Xs + (size_t)(0 + chunk) * PSTR + base) = hv;
        *(s16x8*)(Xs + (size_t)(2 + chunk) * PSTR + base) = lv;
    }
}

// ---------------------------------------------------------------------------
// K5 v4: split-bf16 MFMA conv, merged-K 2-phase, register-headroom schedule.
// Grid 1024 (XCD-swizzled), 512 thr (8 waves), __launch_bounds__(512,1):
//   1 block/CU, compiler free to ~256 VGPR (live ~170) -> NO spills.
// Block: sample b, 2 output rows x 128 px, 64 oc.
// Wave wv: rw=wv&1 (row), qx=wv>>1 (px quarter: 2 nt of 16). acc[4 oct][2 nt].
// Phase = channel chunk (0,1); per phase LDS tile holds BOTH hi and lo planes:
//   [4 rows][65 pairs][16 slots][8ch] = 66,560 B, double-buffered (133 KB).
//   granule g = (row*65+pr)*16 + slot; logical s_lin = slot ^ (pr&7);
//   s_lin = k*8 + u*4 + q  (k=hi/lo plane, u=pixel-in-pair, q=8ch group).
//   Swizzle lives in the SOURCE index (linear ds_write), XOR again on read.
// Per tap: 3 products Wh*Bh + Wl*Bh + Wh*Bl share 4 B-reads and the A ping-pong.
// Schedule: ISSUE(0) WRITE(0) ISSUE(1) bar | taps(0) WRITE(1) bar | taps(1).
// ---------------------------------------------------------------------------
#define NG 4160                    // granules per phase
__launch_bounds__(512, 1)
__global__ void conv_mfma(const unsigned short* __restrict__ Xs,
                          const unsigned short* __restrict__ Wh,
                          const unsigned short* __restrict__ Wl,
                          const float* __restrict__ bias,
                          unsigned short* __restrict__ Ys,
                          float* __restrict__ Yf,
                          int final_layer) {
    const int bid  = blockIdx.x;
    const int wg   = (bid & 7) * 128 + (bid >> 3);   // XCD-bijective swizzle
    const int b    = wg >> 6;
    const int py0  = (wg & 63) * 2;

    const int t  = threadIdx.x;
    const int l  = t & 63;
    const int wv = t >> 6;
    const int lq = l >> 4;
    const int ln = l & 15;
    const int rw = wv & 1;           // output row within block
    const int qx = wv >> 1;          // px quarter (0..3)

    __shared__ __align__(16) unsigned short ldsA[NG * 8];   // 66,560 B
    __shared__ __align__(16) unsigned short ldsB[NG * 8];   // 66,560 B

    f32x4 acc[4][2];
#pragma unroll
    for (int o = 0; o < 4; ++o)
#pragma unroll
        for (int n = 0; n < 2; ++n)
#pragma unroll
            for (int r = 0; r < 4; ++r) acc[o][n][r] = 0.f;

    const size_t pbase = (size_t)b * HW_ * 32;
    const size_t wbase = (size_t)b * OC_ * 9 * 64;

    s16x8 stg[9];

    // Load phase `ch`'s granules into stg regs. Source index carries the swizzle.
#define ISSUE(ch)                                                              \
    {                                                                          \
        _Pragma("unroll")                                                      \
        for (int i = 0; i < 9; ++i) {                                          \
            if (i < 8 || t < (NG - 4096)) {                                    \
                int g    = t + i * 512;                                        \
                int row  = g / 1040;                                           \
                int rem  = g - row * 1040;                                     \
                int pr   = rem >> 4;                                           \
                int slot = rem & 15;                                           \
                int s_lin = slot ^ (pr & 7);                                   \
                int k = s_lin >> 3, u = (s_lin >> 2) & 1, q = s_lin & 3;       \
                int ir = py0 + row - 1;                                        \
                int ic = 2 * pr + u - 1;                                       \
                s16x8 v;                                                       \
                _Pragma("unroll")                                              \
                for (int j = 0; j < 8; ++j) v[j] = 0;                          \
                if ((unsigned)ir < (unsigned)H_ && (unsigned)ic < (unsigned)W_)\
                    v = *(const s16x8*)(Xs + (size_t)(k * 2 + (ch)) * PSTR + pbase \
                        + ((size_t)(ir * W_ + ic)) * 32 + q * 8);              \
                stg[i] = v;                                                    \
            }                                                                  \
        }                                                                      \
    }

    // Linear ds_write of stg (swizzle already applied on source side).
#define WRITE_STG(BUF)                                                         \
    {                                                                          \
        _Pragma("unroll")                                                      \
        for (int i = 0; i < 9; ++i)                                            \
            if (i < 8 || t < (NG - 4096))                                      \
                *(s16x8*)&(BUF)[(t + i * 512) * 8] = stg[i];                   \
    }

    // Tap loop over one phase: buffer BUF, channel base CBASE (0 or 32).
#define TAPS(BUF, CBASE)                                                       \
    {                                                                          \
        s16x8 Ah[2][4], Al[2][4];                                              \
        _Pragma("unroll")                                                      \
        for (int oct = 0; oct < 4; ++oct) {                                    \
            size_t woff = wbase + ((size_t)((oct * 16 + ln) * 9)) * 64         \
                          + (CBASE) + lq * 8;                                  \
            Ah[0][oct] = *(const s16x8*)(Wh + woff);                           \
            Al[0][oct] = *(const s16x8*)(Wl + woff);                           \
        }                                                                      \
        _Pragma("unroll")                                                      \
        for (int tap = 0; tap < 9; ++tap) {                                    \
            const int pp = tap & 1;                                            \
            if (tap < 8) {                                                     \
                _Pragma("unroll")                                              \
                for (int oct = 0; oct < 4; ++oct) {                            \
                    size_t woff = wbase + ((size_t)((oct * 16 + ln) * 9 + tap + 1)) * 64 \
                                  + (CBASE) + lq * 8;                          \
                    Ah[pp ^ 1][oct] = *(const s16x8*)(Wh + woff);              \
                    Al[pp ^ 1][oct] = *(const s16x8*)(Wl + woff);              \
                }                                                              \
            }                                                                  \
            const int ky  = tap / 3;                                           \
            const int kx  = tap - ky * 3;                                       \
            const int row = rw + ky;                                           \
            s16x8 Bh[2], Bl[2];                                                \
            _Pragma("unroll")                                                  \
            for (int nt = 0; nt < 2; ++nt) {                                   \
                int col = qx * 32 + nt * 16 + ln + kx;                         \
                int pr  = col >> 1, u = col & 1;                               \
                int bse = (row * 65 + pr) << 4;                                \
                Bh[nt] = *(const s16x8*)&(BUF)[(bse + ((u * 4 + lq) ^ (pr & 7))) << 3];      \
                Bl[nt] = *(const s16x8*)&(BUF)[(bse + ((8 + u * 4 + lq) ^ (pr & 7))) << 3];  \
            }                                                                  \
            _Pragma("unroll")                                                  \
            for (int oct = 0; oct < 4; ++oct)                                  \
                _Pragma("unroll")                                              \
                for (int nt = 0; nt < 2; ++nt)                                 \
                    acc[oct][nt] = __builtin_amdgcn_mfma_f32_16x16x32_bf16(    \
                        Ah[pp][oct], Bh[nt], acc[oct][nt], 0, 0, 0);           \
            _Pragma("unroll")                                                  \
            for (int oct = 0; oct < 4; ++oct)                                  \
                _Pragma("unroll")                                              \
                for (int nt = 0; nt < 2; ++nt)                                 \
                    acc[oct][nt] = __builtin_amdgcn_mfma_f32_16x16x32_bf16(    \
                        Al[pp][oct], Bh[nt], acc[oct][nt], 0, 0, 0);           \
            _Pragma("unroll")                                                  \
            for (int oct = 0; oct < 4; ++oct)                                  \
                _Pragma("unroll")                                              \
                for (int nt = 0; nt < 2; ++nt)                                 \
                    acc[oct][nt] = __builtin_amdgcn_mfma_f32_16x16x32_bf16(    \
                        Ah[pp][oct], Bl[nt], acc[oct][nt], 0, 0, 0);           \
        }                                                                      \
    }

    // ---- schedule ----
    ISSUE(0);
    WRITE_STG(ldsA);                 // one vmcnt wait (prologue, once)
    ISSUE(1);                        // pinned before barrier; hides under taps(0)
    __syncthreads();

    TAPS(ldsA, 0);
    WRITE_STG(ldsB);                 // stg(1) long arrived; ldsB untouched yet
    __syncthreads();

    TAPS(ldsB, 32);

    // ---- epilogue: bias + store ----
    float bia[4][4];
#pragma unroll
    for (int oct = 0; oct < 4; ++oct)
#pragma unroll
        for (int r = 0; r < 4; ++r)
            bia[oct][r] = bias[b * OC_ + oct * 16 + lq * 4 + r];

    const int orow = py0 + rw;
    if (!final_layer) {
#pragma unroll
        for (int oct = 0; oct < 4; ++oct)
#pragma unroll
            for (int nt = 0; nt < 2; ++nt) {
                int px = qx * 32 + nt * 16 + ln;
                size_t pxl = (size_t)b * HW_ + orow * W_ + px;
                int oc0   = oct * 16 + lq * 4;
                int chunk = oc0 >> 5;
                int off   = oc0 & 31;
                s16x4 hv, lv;
#pragma unroll
                for (int r = 0; r < 4; ++r) {
                    float v = acc[oct][nt][r] + bia[oct][r];
                    unsigned short h = f2bf(v);
                    hv[r] = (short)h;
                    lv[r] = (short)f2bf(v - bf2f(h));
                }
                *(s16x4*)(Ys + (size_t)(0 + chunk) * PSTR + pxl * 32 + off) = hv;
                *(s16x4*)(Ys + (size_t)(2 + chunk) * PSTR + pxl * 32 + off) = lv;
            }
    } else {
#pragma unroll
        for (int oct = 0; oct < 4; ++oct)
#pragma unroll
            for (int nt = 0; nt < 2; ++nt) {
                int px = qx * 32 + nt * 16 + ln;
#pragma unroll
                for (int r = 0; r < 4; ++r) {
                    int oc = oct * 16 + lq * 4 + r;
                    Yf[((size_t)(b * OC_ + oc)) * HW_ + orow * W_ + px] =
                        acc[oct][nt][r] + bia[oct][r];
                }
            }
    }
#undef ISSUE
#undef WRITE_STG
#undef TAPS
}

// ---------------------------------------------------------------------------
// Launch
// ---------------------------------------------------------------------------
extern "C" void kernel_launch(void* const* d_in, const int* in_sizes, int n_in,
                              void* d_out, int out_size, void* d_ws, size_t ws_size,
                              hipStream_t stream) {
    const float* x   = (const float*)d_in[0];
    const float* cw1 = (const float*)d_in[1];
    const float* cw2 = (const float*)d_in[2];
    const float* w1  = (const float*)d_in[3];
    const float* w2  = (const float*)d_in[4];
    const float* w3  = (const float*)d_in[5];
    const float* b1  = (const float*)d_in[6];
    const float* b2  = (const float*)d_in[7];
    const float* b3  = (const float*)d_in[8];

    char* ws = (char*)d_ws;
    float* pooled = (float*)(ws + 0);            //  4 KB
    float* coeff  = (float*)(ws + 4096);         // 16 KB
    float* ab_all = (float*)(ws + 20480);        // 12 KB
    const size_t WSZ = (size_t)B_ * OC_ * 9 * 64 * 2;   // 1,179,648 B per W array
    unsigned short* Wh1 = (unsigned short*)(ws + 32768);
    unsigned short* Wl1 = (unsigned short*)(ws + 32768 + 1 * WSZ);
    unsigned short* Wh2 = (unsigned short*)(ws + 32768 + 2 * WSZ);
    unsigned short* Wl2 = (unsigned short*)(ws + 32768 + 3 * WSZ);
    unsigned short* Wh3 = (unsigned short*)(ws + 32768 + 4 * WSZ);
    unsigned short* Wl3 = (unsigned short*)(ws + 32768 + 5 * WSZ);
    const size_t SOFF = 32768 + 6 * WSZ;                 // 7,110,656
    const size_t SSZ  = 4 * PSTR * 2;                    // 67,108,864 B per stage
    unsigned short* S0 = (unsigned short*)(ws + SOFF);
    unsigned short* S1 = (unsigned short*)(ws + SOFF + SSZ);
    // total = 141,328,384 B (unchanged)

    float* ab1 = ab_all;
    float* ab2 = ab_all + B_ * OC_;
    float* ab3 = ab_all + 2 * B_ * OC_;

    pool_kernel<<<B_ * C_, 256, 0, stream>>>(x, pooled);
    control_kernel<<<B_, 64, 0, stream>>>(pooled, cw1, cw2, b1, b2, b3, coeff, ab_all);
    {
        dim3 g(2304, 3);
        aggw_split<<<g, 256, 0, stream>>>(coeff, w1, w2, w3,
                                          Wh1, Wl1, Wh2, Wl2, Wh3, Wl3);
    }
    {
        dim3 g(HW_ / 64, B_);
        xcvt_kernel<<<g, 256, 0, stream>>>(x, S0);
    }
    conv_mfma<<<1024, 512, 0, stream>>>(S0, Wh1, Wl1, ab1, S1, nullptr, 0);
    conv_mfma<<<1024, 512, 0, stream>>>(S1, Wh2, Wl2, ab2, S0, nullptr, 0);
    conv_mfma<<<1024, 512, 0, stream>>>(S0, Wh3, Wl3, ab3, nullptr, (float*)d_out, 1);
}